// Round 1
// baseline (1434.428 us; speedup 1.0000x reference)
//
#include <hip/hip_runtime.h>
#include <hip/hip_fp16.h>
#include <hip/hip_cooperative_groups.h>

namespace cg = cooperative_groups;

#define NN 262144
#define NCC 4096
#define DD 5
#define KK 4
#define PRE_IT 3
#define POST_IT 3
#define COARSE_IT 10
#define WJ ((float)(2.0/3.0))

// ---------------- bucketing: histogram of P_cols over NC buckets ----------------
__global__ __launch_bounds__(1024) void k_hist(const int4* __restrict__ pc4,
                                               unsigned* __restrict__ cnt) {
  __shared__ unsigned h[NCC];
  const int tid = threadIdx.x;
  for (int q = tid; q < NCC; q += 1024) h[q] = 0u;
  __syncthreads();
  const int base = blockIdx.x * 4096;
#pragma unroll
  for (int rr = 0; rr < 4; ++rr) {
    int4 pc = pc4[base + rr * 1024 + tid];
    atomicAdd(&h[pc.x], 1u); atomicAdd(&h[pc.y], 1u);
    atomicAdd(&h[pc.z], 1u); atomicAdd(&h[pc.w], 1u);
  }
  __syncthreads();
  for (int q = tid; q < NCC; q += 1024) { unsigned v = h[q]; if (v) atomicAdd(&cnt[q], v); }
}

// ---------------- exclusive scan of 4096 counts (single block) ----------------
__global__ __launch_bounds__(1024) void k_scan(unsigned* __restrict__ cnt_cursor,
                                               unsigned* __restrict__ offs) {
  __shared__ unsigned sv[1024];
  const int t = threadIdx.x;
  unsigned c0 = cnt_cursor[t*4+0], c1 = cnt_cursor[t*4+1],
           c2 = cnt_cursor[t*4+2], c3 = cnt_cursor[t*4+3];
  unsigned s = c0 + c1 + c2 + c3;
  sv[t] = s; __syncthreads();
  for (int off = 1; off < 1024; off <<= 1) {
    unsigned v = (t >= off) ? sv[t-off] : 0u;
    __syncthreads();
    sv[t] += v;
    __syncthreads();
  }
  unsigned run = sv[t] - s;
  unsigned o0 = run, o1 = run + c0, o2 = o1 + c1, o3 = o2 + c2;
  offs[t*4+0] = o0; offs[t*4+1] = o1; offs[t*4+2] = o2; offs[t*4+3] = o3;
  // cursor (aliases cnt) = bucket write positions for the scatter kernel
  cnt_cursor[t*4+0] = o0; cnt_cursor[t*4+1] = o1;
  cnt_cursor[t*4+2] = o2; cnt_cursor[t*4+3] = o3;
  if (t == 1023) offs[4096] = sv[1023];
}

// ---------------- ranked scatter of (row,k) pairs into buckets ----------------
__global__ __launch_bounds__(1024) void k_scatter(const int4* __restrict__ pc4,
                                                  unsigned* __restrict__ cursor,
                                                  unsigned* __restrict__ pairs) {
  __shared__ unsigned h[NCC];
  __shared__ unsigned basec[NCC];
  const int tid = threadIdx.x;
  for (int q = tid; q < NCC; q += 1024) h[q] = 0u;
  __syncthreads();
  const int rbase = blockIdx.x * 4096;
  int4 pc[4];
#pragma unroll
  for (int rr = 0; rr < 4; ++rr) {
    pc[rr] = pc4[rbase + rr * 1024 + tid];
    atomicAdd(&h[pc[rr].x], 1u); atomicAdd(&h[pc[rr].y], 1u);
    atomicAdd(&h[pc[rr].z], 1u); atomicAdd(&h[pc[rr].w], 1u);
  }
  __syncthreads();
  for (int q = tid; q < NCC; q += 1024) {
    unsigned v = h[q];
    basec[q] = v ? atomicAdd(&cursor[q], v) : 0u;
  }
  __syncthreads();
  for (int q = tid; q < NCC; q += 1024) h[q] = 0u;
  __syncthreads();
#pragma unroll
  for (int rr = 0; rr < 4; ++rr) {
    const unsigned g = (unsigned)(rbase + rr * 1024 + tid);
    unsigned r;
    r = atomicAdd(&h[pc[rr].x], 1u); pairs[basec[pc[rr].x] + r] = (g << 2) | 0u;
    r = atomicAdd(&h[pc[rr].y], 1u); pairs[basec[pc[rr].y] + r] = (g << 2) | 1u;
    r = atomicAdd(&h[pc[rr].z], 1u); pairs[basec[pc[rr].z] + r] = (g << 2) | 2u;
    r = atomicAdd(&h[pc[rr].w], 1u); pairs[basec[pc[rr].w] + r] = (g << 2) | 3u;
  }
}

// ---------------- the whole V-cycle: one cooperative kernel ----------------
// LDS: fp16 Ac slab (16 rows x 4096) 128 KB + fp32 rowbuf 16 KB + wdiag/bc 128 B
__global__ __launch_bounds__(1024, 4) void k_mega(
    const float* __restrict__ b, const float* __restrict__ x_in,
    const float* __restrict__ A_vals, const float* __restrict__ P_vals,
    const int* __restrict__ A_cols, const int* __restrict__ P_cols,
    const int* __restrict__ num_p,
    const unsigned* __restrict__ offs, const unsigned* __restrict__ pairs,
    float* __restrict__ partials, float* __restrict__ x2,
    float* __restrict__ xcA, float* __restrict__ xcB,
    float* __restrict__ out) {
  extern __shared__ char smem[];
  __half* slab  = (__half*)smem;                           // 131072 B
  float* rowbuf = (float*)(smem + 131072);                 // 16384 B
  float* wdiag  = (float*)(smem + 131072 + 16384);         // 64 B  (W / diag_c, fp32)
  float* bcl    = (float*)(smem + 131072 + 16384 + 64);    // 64 B  (block's 16 bc entries)

  cg::grid_group grid = cg::this_grid();
  const int tid = threadIdx.x;
  const int blk = blockIdx.x;
  const int g = (blk << 10) + tid;   // this thread's fine row

  // ---- build phase: coarse rows [blk*16, blk*16+16), one 16KB fp32 row at a time ----
  for (int rr = 0; rr < 16; ++rr) {
    const int c1 = (blk << 4) + rr;
    for (int q = tid; q < NCC; q += 1024) rowbuf[q] = 0.f;
    __syncthreads();
    const unsigned p0 = offs[c1], p1 = offs[c1 + 1];
    const unsigned items = (p1 - p0) * DD;   // work item = (pair, j)
    for (unsigned wk = tid; wk < items; wk += 1024) {
      const unsigned p = p0 + wk / DD;
      const int j = (int)(wk - (wk / DD) * DD);
      const unsigned e = pairs[p];
      const unsigned i = e >> 2, a = e & 3u;
      const float pv = P_vals[i * KK + a];
      const int i2 = A_cols[i * DD + j];
      const float coeff = pv * A_vals[i * DD + j];
      const int4 pc2 = ((const int4*)P_cols)[i2];
      const float4 pv2 = ((const float4*)P_vals)[i2];
      atomicAdd(&rowbuf[pc2.x], coeff * pv2.x);
      atomicAdd(&rowbuf[pc2.y], coeff * pv2.y);
      atomicAdd(&rowbuf[pc2.z], coeff * pv2.z);
      atomicAdd(&rowbuf[pc2.w], coeff * pv2.w);
    }
    __syncthreads();
    if (tid == 0) wdiag[rr] = WJ / rowbuf[c1];   // fp32 diagonal
    for (int q = tid; q < NCC; q += 1024) slab[(rr << 12) + q] = __float2half(rowbuf[q]);
    __syncthreads();
  }

  const int num = num_p[0];
  if (num <= 0) { out[g] = x_in[g]; return; }

  // ---- persistent per-row registers (reused across all 14 fine sweeps) ----
  float av[DD]; int ac[DD];
#pragma unroll
  for (int j = 0; j < DD; ++j) { av[j] = A_vals[g * DD + j]; ac[j] = A_cols[g * DD + j]; }
  const float bg = b[g];
  const float wdg = WJ / av[0];
  const int4 pcg = ((const int4*)P_cols)[g];
  const float4 pvg = ((const float4*)P_vals)[g];

  const float* xr = x_in;  // current x (read side)
  int wi = 0;              // 0 -> write x2, 1 -> write out; 6 writes/cycle => final lands in out

  for (int cyc = 0; cyc < num; ++cyc) {
    // ---- pre-smooth x3 ----
    for (int it = 0; it < PRE_IT; ++it) {
      float s = 0.f;
#pragma unroll
      for (int j = 0; j < DD; ++j) s += av[j] * xr[ac[j]];
      const float xn = xr[g] + (bg - s) * wdg;
      float* wb = (wi == 0) ? x2 : out;
      wb[g] = xn;
      xr = wb; wi ^= 1;
      grid.sync();
    }
    // ---- residual + block-partial restriction (deterministic, no global atomics) ----
    {
      float s = 0.f;
#pragma unroll
      for (int j = 0; j < DD; ++j) s += av[j] * xr[ac[j]];
      const float r = bg - s;
      for (int q = tid; q < NCC; q += 1024) rowbuf[q] = 0.f;
      __syncthreads();
      atomicAdd(&rowbuf[pcg.x], pvg.x * r);
      atomicAdd(&rowbuf[pcg.y], pvg.y * r);
      atomicAdd(&rowbuf[pcg.z], pvg.z * r);
      atomicAdd(&rowbuf[pcg.w], pvg.w * r);
      __syncthreads();
      for (int q = tid; q < NCC; q += 1024) partials[(blk << 12) + q] = rowbuf[q];
      grid.sync();
    }
    // ---- reduce partials -> bc (block-local 16 entries) + coarse iteration 0 ----
    {
      for (int q = tid; q < 4096; q += 1024) {
        const int t2 = q >> 4, c = q & 15;
        rowbuf[q] = partials[(t2 << 12) + (blk << 4) + c];
      }
      __syncthreads();
      if (tid < 16) {
        float sum = 0.f;
#pragma unroll 8
        for (int t2 = 0; t2 < 256; ++t2) sum += rowbuf[(t2 << 4) + tid];
        bcl[tid] = sum;
        xcA[(blk << 4) + tid] = sum * wdiag[tid];   // xc1 = W*bc/diag (xc0 = 0)
      }
      grid.sync();
    }
    // ---- coarse Jacobi iterations 1..9 (LDS-resident fp16 Ac) ----
    const float* xc_cur = xcA;
    float* xc_nxt = xcB;
    for (int it = 1; it < COARSE_IT; ++it) {
      const int w = tid >> 6, l = tid & 63;        // wave w covers cols [256w, 256w+256)
      const float4 xv = ((const float4*)xc_cur)[(w << 6) + l];
      float acc[16];
#pragma unroll
      for (int r2 = 0; r2 < 16; ++r2) {
        const __half2* hp2 = (const __half2*)(slab + (r2 << 12) + (w << 8) + (l << 2));
        const float2 f01 = __half22float2(hp2[0]);
        const float2 f23 = __half22float2(hp2[1]);
        acc[r2] = f01.x * xv.x + f01.y * xv.y + f23.x * xv.z + f23.y * xv.w;
      }
#pragma unroll
      for (int r2 = 0; r2 < 16; ++r2) {
        float v = acc[r2];
        v += __shfl_down(v, 32); v += __shfl_down(v, 16); v += __shfl_down(v, 8);
        v += __shfl_down(v, 4);  v += __shfl_down(v, 2);  v += __shfl_down(v, 1);
        acc[r2] = v;
      }
      if (l == 0) {
#pragma unroll
        for (int r2 = 0; r2 < 16; ++r2) rowbuf[(w << 4) + r2] = acc[r2];
      }
      __syncthreads();
      if (tid < 16) {
        float y = 0.f;
#pragma unroll
        for (int w2 = 0; w2 < 16; ++w2) y += rowbuf[(w2 << 4) + tid];
        const float xo = xc_cur[(blk << 4) + tid];
        xc_nxt[(blk << 4) + tid] = xo + (bcl[tid] - y) * wdiag[tid];
      }
      float* tmp = (float*)xc_cur; xc_cur = xc_nxt; xc_nxt = tmp;
      grid.sync();
    }
    // ---- prolongation (in-place; xr is never x_in here since PRE_IT >= 1) ----
    {
      float* xw = (float*)xr;
      const float corr = pvg.x * xc_cur[pcg.x] + pvg.y * xc_cur[pcg.y] +
                         pvg.z * xc_cur[pcg.z] + pvg.w * xc_cur[pcg.w];
      xw[g] = xr[g] + corr;
      grid.sync();
    }
    // ---- post-smooth x3 ----
    for (int it = 0; it < POST_IT; ++it) {
      float s = 0.f;
#pragma unroll
      for (int j = 0; j < DD; ++j) s += av[j] * xr[ac[j]];
      const float xn = xr[g] + (bg - s) * wdg;
      float* wb = (wi == 0) ? x2 : out;
      wb[g] = xn;
      xr = wb; wi ^= 1;
      if (!(cyc == num - 1 && it == POST_IT - 1)) grid.sync();
    }
  }
}

extern "C" void kernel_launch(void* const* d_in, const int* in_sizes, int n_in,
                              void* d_out, int out_size, void* d_ws, size_t ws_size,
                              hipStream_t stream) {
  (void)in_sizes; (void)n_in; (void)out_size; (void)ws_size;
  const float* b      = (const float*)d_in[0];
  const float* x_in   = (const float*)d_in[1];
  const float* A_vals = (const float*)d_in[2];
  const float* P_vals = (const float*)d_in[3];
  const int*   A_cols = (const int*)d_in[4];
  const int*   P_cols = (const int*)d_in[5];
  const int*   num_p  = (const int*)d_in[6];
  float* out = (float*)d_out;

  char* ws = (char*)d_ws;                                   // ~9.5 MB total
  unsigned* cnt   = (unsigned*)(ws + 0);                    // 16 KB (becomes cursor)
  unsigned* offs  = (unsigned*)(ws + 16384);                // 4097 u32
  float*    xcA   = (float*)(ws + 40960);                   // 16 KB
  float*    xcB   = (float*)(ws + 57344);                   // 16 KB
  unsigned* pairs = (unsigned*)(ws + 73728);                // 4 MB
  float* partials = (float*)(ws + 73728 + 4194304);         // 4 MB
  float* x2       = (float*)(ws + 73728 + 8388608);         // 1 MB

  hipMemsetAsync(cnt, 0, NCC * sizeof(unsigned), stream);
  hipLaunchKernelGGL(k_hist,    dim3(64), dim3(1024), 0, stream, (const int4*)P_cols, cnt);
  hipLaunchKernelGGL(k_scan,    dim3(1),  dim3(1024), 0, stream, cnt, offs);
  hipLaunchKernelGGL(k_scatter, dim3(64), dim3(1024), 0, stream, (const int4*)P_cols, cnt, pairs);

  const unsigned smem_bytes = 131072 + 16384 + 64 + 64;     // 147584 B < 160 KB
  hipFuncSetAttribute((const void*)k_mega,
                      hipFuncAttributeMaxDynamicSharedMemorySize, (int)smem_bytes);
  void* args[] = { (void*)&b, (void*)&x_in, (void*)&A_vals, (void*)&P_vals,
                   (void*)&A_cols, (void*)&P_cols, (void*)&num_p,
                   (void*)&offs, (void*)&pairs, (void*)&partials, (void*)&x2,
                   (void*)&xcA, (void*)&xcB, (void*)&out };
  hipLaunchCooperativeKernel((void*)k_mega, dim3(256), dim3(1024), args, smem_bytes, stream);
}